// Round 1
// 1455.867 us; speedup vs baseline: 1.0874x; 1.0874x over previous
//
#include <hip/hip_runtime.h>

#define TILE_E 128

typedef __attribute__((ext_vector_type(8))) short bf16x8;
typedef __attribute__((ext_vector_type(4))) float f32x4;

__device__ __forceinline__ unsigned int f2bf(float f) {
    union { float f; unsigned int u; } v; v.f = f;
    return (v.u + 0x7FFFu + ((v.u >> 16) & 1u)) >> 16;   // RNE bf16
}
// native packed f32->bf16 (RNE), 1 instr per 2 values
__device__ __forceinline__ unsigned int cvt_pk_bf16(float lo, float hi) {
    unsigned int r;
    asm("v_cvt_pk_bf16_f32 %0, %1, %2" : "=v"(r) : "v"(lo), "v"(hi));
    return r;
}
__device__ __forceinline__ float fsigmoid(float x) { return 1.0f / (1.0f + __expf(-x)); }
__device__ __forceinline__ float fsilu(float x) { return x * fsigmoid(x); }

// bf16 weight pool offsets (elements), frag-linear layout
#define O_EL1 0
#define O_EG1 12288
#define O_EL2 24576
#define O_EG2 28672
#define O_NL1 32768
#define O_NG1 45056
#define O_NL2 57344
#define O_NG2 61440

// Convert fp32 [64 x K] weights to bf16 in B-fragment-linear order:
// off(n,k) = (((n>>4)*(K/32) + (k>>5))*4 + ((k>>3)&3))*128 + (n&15)*8 + (k&7)
__global__ void prep_weights(const float* el1, const float* eg1, const float* el2, const float* eg2,
                             const float* nl1, const float* ng1, const float* nl2, const float* ng2,
                             unsigned short* wout) {
    int tid = blockIdx.x * 256 + threadIdx.x;
    if (tid >= 65536) return;
    int idx = tid; const float* s; int base, K;
    if (idx < 12288)      { s = el1; base = O_EL1; K = 192; }
    else if (idx < 24576) { idx -= 12288; s = eg1; base = O_EG1; K = 192; }
    else if (idx < 28672) { idx -= 24576; s = el2; base = O_EL2; K = 64; }
    else if (idx < 32768) { idx -= 28672; s = eg2; base = O_EG2; K = 64; }
    else if (idx < 45056) { idx -= 32768; s = nl1; base = O_NL1; K = 192; }
    else if (idx < 57344) { idx -= 45056; s = ng1; base = O_NG1; K = 192; }
    else if (idx < 61440) { idx -= 57344; s = nl2; base = O_NL2; K = 64; }
    else                  { idx -= 61440; s = ng2; base = O_NG2; K = 64; }
    int n = (K == 192) ? (idx / 192) : (idx >> 6);
    int k = idx - n * K;
    int off = (((n >> 4) * (K >> 5) + (k >> 5)) * 4 + ((k >> 3) & 3)) * 128 + ((n & 15) << 3) + (k & 7);
    wout[base + off] = (unsigned short)f2bf(s[idx]);
}

__global__ void vinit(const float* __restrict__ node_feat, float* __restrict__ out_v, int n) {
    int i = blockIdx.x * 256 + threadIdx.x;
    if (i < n) out_v[i] = node_feat[i];
}

// One full GatedMLP for this wave's 16 edge rows. X (A-frag-linear bf16) in Xw,
// HGw is the wave-private LDS round-trip buffer (1024 shorts) for h1/g1.
__device__ __forceinline__ void gated_mlp(
    const unsigned short* __restrict__ Xw, unsigned short* __restrict__ HGw,
    const unsigned short* __restrict__ wb,
    int oL1, int oL2, int oG1, int oG2,
    const float* __restrict__ bL1, const float* __restrict__ bL2,
    const float* __restrict__ bG1, const float* __restrict__ bG2,
    int lane, f32x4 prod[4])
{
    const int qp = lane >> 4, ln = lane & 15;

    // hoist A1 fragments: K=192 -> 6 k-steps
    bf16x8 a1[6];
    #pragma unroll
    for (int t = 0; t < 6; ++t)
        a1[t] = *(const bf16x8*)(Xw + t * 512 + lane * 8);

    f32x4 acc2h[4], acc2g[4];

    #pragma unroll
    for (int br = 0; br < 2; ++br) {     // br=0: layers branch, br=1: gates branch
        const int o1 = br ? oG1 : oL1;
        const int o2 = br ? oG2 : oL2;
        const float* b1 = br ? bG1 : bL1;

        // ---- layer 1: [16 x 192] @ [192 x 64] ----
        f32x4 acc[4];
        #pragma unroll
        for (int nt = 0; nt < 4; ++nt)
            acc[nt] = (f32x4){0.f, 0.f, 0.f, 0.f};
        #pragma unroll
        for (int nt = 0; nt < 4; ++nt)
            #pragma unroll
            for (int t = 0; t < 6; ++t) {
                bf16x8 bfr = *(const bf16x8*)(wb + o1 + (nt * 6 + t) * 512 + lane * 8);
                acc[nt] = __builtin_amdgcn_mfma_f32_16x16x32_bf16(a1[t], bfr, acc[nt], 0, 0, 0);
            }
        // bias + SiLU, write hidden to HG (A-frag-linear, K=64 -> 2 k-steps)
        // pack pairs (r, r+1) via v_cvt_pk_bf16_f32, store lo/hi b16
        #pragma unroll
        for (int nt = 0; nt < 4; ++nt) {
            const float bias = b1[nt * 16 + ln];
            const int f = nt * 16 + ln, t2 = f >> 5, q2 = (f >> 3) & 3, j2 = f & 7;
            unsigned short* hp = HGw + t2 * 512 + q2 * 128 + j2;
            #pragma unroll
            for (int r2 = 0; r2 < 4; r2 += 2) {
                unsigned int p = cvt_pk_bf16(fsilu(acc[nt][r2] + bias),
                                             fsilu(acc[nt][r2 + 1] + bias));
                hp[(qp * 4 + r2) * 8]     = (unsigned short)p;
                hp[(qp * 4 + r2 + 1) * 8] = (unsigned short)(p >> 16);
            }
        }
        asm volatile("s_waitcnt lgkmcnt(0)" ::: "memory");  // wave-local LDS RAW fence

        bf16x8 a2[2];
        #pragma unroll
        for (int t2 = 0; t2 < 2; ++t2)
            a2[t2] = *(const bf16x8*)(HGw + t2 * 512 + lane * 8);

        // ---- layer 2: [16 x 64] @ [64 x 64] ----
        f32x4* acc2 = br ? acc2g : acc2h;
        #pragma unroll
        for (int nt = 0; nt < 4; ++nt)
            acc2[nt] = (f32x4){0.f, 0.f, 0.f, 0.f};
        #pragma unroll
        for (int nt = 0; nt < 4; ++nt)
            #pragma unroll
            for (int t2 = 0; t2 < 2; ++t2) {
                bf16x8 bfr = *(const bf16x8*)(wb + o2 + (nt * 2 + t2) * 512 + lane * 8);
                acc2[nt] = __builtin_amdgcn_mfma_f32_16x16x32_bf16(a2[t2], bfr, acc2[nt], 0, 0, 0);
            }
    }

    #pragma unroll
    for (int nt = 0; nt < 4; ++nt) {
        const float b2v = bL2[nt * 16 + ln], bg2v = bG2[nt * 16 + ln];
        #pragma unroll
        for (int r = 0; r < 4; ++r)
            prod[nt][r] = fsilu(acc2h[nt][r] + b2v) * fsigmoid(acc2g[nt][r] + bg2v);
    }
}

__global__ __launch_bounds__(512, 4) void m3g_main(
    const float* __restrict__ node_feat, const float* __restrict__ edge_feat,
    const float* __restrict__ rbf, const int* __restrict__ src, const int* __restrict__ dst,
    const unsigned short* __restrict__ wb,
    const float* __restrict__ el1b, const float* __restrict__ el2b,
    const float* __restrict__ eg1b, const float* __restrict__ eg2b,
    const float* __restrict__ nl1b, const float* __restrict__ nl2b,
    const float* __restrict__ ng1b, const float* __restrict__ ng2b,
    const float* __restrict__ eww, const float* __restrict__ nww,
    float* __restrict__ out_e, float* __restrict__ out_v, int E)
{
    // LDS: 49152 (Xs) + 16384 (HGs) + 512 (dsts) = 66048 B -> 2 blocks/CU = 16 waves/CU
    __shared__ unsigned short Xs[128 * 192];   // A-frag-linear bf16, 8 regions of 16x192
    __shared__ unsigned short HGs[8 * 1024];   // per-wave hidden round-trip (1 row-tile)
    __shared__ int dsts[128];

    const int tid = threadIdx.x;
    const int e0 = blockIdx.x * TILE_E;

    if (tid < 128) { int eg = e0 + tid; dsts[tid] = (eg < E) ? dst[eg] : 0; }

    {   // stage X = [vi | vj | edge_feat] as bf16, frag-linear. 4 threads/edge, 16 cols each.
        const int el = tid >> 2, cb = (tid & 3) * 16;
        const int eg = min(e0 + el, E - 1);
        const int reg = el >> 4;              // wave index owning this edge
        const int m = el & 15;
        const float* r0 = node_feat + (size_t)src[eg] * 64;
        const float* r1 = node_feat + (size_t)dst[eg] * 64;
        const float* r2 = edge_feat + (size_t)eg * 64;
        const float* rows[3] = { r0, r1, r2 };
        #pragma unroll
        for (int s = 0; s < 3; ++s) {
            const float4* rp = (const float4*)(rows[s] + cb);
            #pragma unroll
            for (int o = 0; o < 2; ++o) {
                float4 f0 = rp[o * 2], f1 = rp[o * 2 + 1];
                uint4 u;
                u.x = cvt_pk_bf16(f0.x, f0.y);
                u.y = cvt_pk_bf16(f0.z, f0.w);
                u.z = cvt_pk_bf16(f1.x, f1.y);
                u.w = cvt_pk_bf16(f1.z, f1.w);
                int kk = s * 64 + cb + o * 8;
                int t = kk >> 5, q = (kk >> 3) & 3;
                *(uint4*)&Xs[reg * 3072 + (t * 4 + q) * 128 + m * 8] = u;
            }
        }
    }
    __syncthreads();   // only block-wide barrier; everything below is wave-local

    const int w = tid >> 6, lane = tid & 63;
    const int qp = lane >> 4, ln = lane & 15;
    const unsigned short* Xw = Xs + w * 3072;
    unsigned short* HGw = HGs + w * 1024;

    // ================= edge MLP =================
    f32x4 prodE[4];
    gated_mlp(Xw, HGw, wb, O_EL1, O_EL2, O_EG1, O_EG2, el1b, el2b, eg1b, eg2b, lane, prodE);

    float ewv[4][9];
    #pragma unroll
    for (int nt = 0; nt < 4; ++nt)
        #pragma unroll
        for (int ri = 0; ri < 9; ++ri)
            ewv[nt][ri] = eww[(nt * 16 + ln) * 9 + ri];

    #pragma unroll
    for (int r = 0; r < 4; ++r) {
        const int m = qp * 4 + r, el = w * 16 + m, eg = e0 + el;
        if (eg < E) {
            float rb[9];
            #pragma unroll
            for (int ri = 0; ri < 9; ++ri) rb[ri] = rbf[(size_t)eg * 9 + ri];
            #pragma unroll
            for (int nt = 0; nt < 4; ++nt) {
                float rw = 0.0f;
                #pragma unroll
                for (int ri = 0; ri < 9; ++ri) rw += rb[ri] * ewv[nt][ri];
                const int f = nt * 16 + ln;
                float en = edge_feat[(size_t)eg * 64 + f] + prodE[nt][r] * rw;
                out_e[(size_t)eg * 64 + f] = en;
                // overwrite e-section of X with e_new (k = 128 + f); wave-local rows only
                const int kk = 128 + f, t = kk >> 5, q = (kk >> 3) & 3;
                Xs[w * 3072 + (t * 4 + q) * 128 + m * 8 + (f & 7)] = (unsigned short)f2bf(en);
            }
        }
    }
    asm volatile("s_waitcnt lgkmcnt(0)" ::: "memory");

    // ================= node MLP =================
    f32x4 prodN[4];
    gated_mlp(Xw, HGw, wb, O_NL1, O_NL2, O_NG1, O_NG2, nl1b, nl2b, ng1b, ng2b, lane, prodN);

    float nwv[4][9];
    #pragma unroll
    for (int nt = 0; nt < 4; ++nt)
        #pragma unroll
        for (int ri = 0; ri < 9; ++ri)
            nwv[nt][ri] = nww[(nt * 16 + ln) * 9 + ri];

    #pragma unroll
    for (int r = 0; r < 4; ++r) {
        const int m = qp * 4 + r, el = w * 16 + m, eg = e0 + el;
        if (eg < E) {
            float rb[9];
            #pragma unroll
            for (int ri = 0; ri < 9; ++ri) rb[ri] = rbf[(size_t)eg * 9 + ri];
            const int dn = dsts[el];
            #pragma unroll
            for (int nt = 0; nt < 4; ++nt) {
                float rw = 0.0f;
                #pragma unroll
                for (int ri = 0; ri < 9; ++ri) rw += rb[ri] * nwv[nt][ri];
                float mess = prodN[nt][r] * rw;
                unsafeAtomicAdd(&out_v[(size_t)dn * 64 + nt * 16 + ln], mess);
            }
        }
    }
}

extern "C" void kernel_launch(void* const* d_in, const int* in_sizes, int n_in,
                              void* d_out, int out_size, void* d_ws, size_t ws_size,
                              hipStream_t stream) {
    const float* node_feat = (const float*)d_in[0];
    const float* edge_feat = (const float*)d_in[1];
    const float* rbf  = (const float*)d_in[2];
    const int*   src  = (const int*)d_in[3];
    const int*   dst  = (const int*)d_in[4];
    const float* el1w = (const float*)d_in[5];
    const float* el1b = (const float*)d_in[6];
    const float* el2w = (const float*)d_in[7];
    const float* el2b = (const float*)d_in[8];
    const float* eg1w = (const float*)d_in[9];
    const float* eg1b = (const float*)d_in[10];
    const float* eg2w = (const float*)d_in[11];
    const float* eg2b = (const float*)d_in[12];
    const float* nl1w = (const float*)d_in[13];
    const float* nl1b = (const float*)d_in[14];
    const float* nl2w = (const float*)d_in[15];
    const float* nl2b = (const float*)d_in[16];
    const float* ng1w = (const float*)d_in[17];
    const float* ng1b = (const float*)d_in[18];
    const float* ng2w = (const float*)d_in[19];
    const float* ng2b = (const float*)d_in[20];
    const float* eww  = (const float*)d_in[21];
    const float* nww  = (const float*)d_in[22];

    const int E = in_sizes[1] / 64;
    const int N = in_sizes[0] / 64;
    float* out_e = (float*)d_out;
    float* out_v = out_e + (size_t)E * 64;
    unsigned short* wbf = (unsigned short*)d_ws;

    prep_weights<<<256, 256, 0, stream>>>(el1w, eg1w, el2w, eg2w, nl1w, ng1w, nl2w, ng2w, wbf);
    vinit<<<(N * 64 + 255) / 256, 256, 0, stream>>>(node_feat, out_v, N * 64);
    m3g_main<<<(E + TILE_E - 1) / TILE_E, 512, 0, stream>>>(
        node_feat, edge_feat, rbf, src, dst, wbf,
        el1b, el2b, eg1b, eg2b, nl1b, nl2b, ng1b, ng2b,
        eww, nww, out_e, out_v, E);
}